// Round 12
// baseline (1671.881 us; speedup 1.0000x reference)
//
#include <hip/hip_runtime.h>
#include <hip/hip_bf16.h>

__device__ __forceinline__ float tanh_fast(float x){
    float e = __expf(2.0f*x);
    return 1.0f - 2.0f/(e + 1.0f);
}

// one GEMM row: 8 electrons (two float4 of transposed activations) x 4 cols
#define ROWT8(ALo, AHi, W_) do{                                       \
    acc[0][0]+=(ALo).x*(W_).x; acc[0][1]+=(ALo).x*(W_).y;             \
    acc[0][2]+=(ALo).x*(W_).z; acc[0][3]+=(ALo).x*(W_).w;             \
    acc[1][0]+=(ALo).y*(W_).x; acc[1][1]+=(ALo).y*(W_).y;             \
    acc[1][2]+=(ALo).y*(W_).z; acc[1][3]+=(ALo).y*(W_).w;             \
    acc[2][0]+=(ALo).z*(W_).x; acc[2][1]+=(ALo).z*(W_).y;             \
    acc[2][2]+=(ALo).z*(W_).z; acc[2][3]+=(ALo).z*(W_).w;             \
    acc[3][0]+=(ALo).w*(W_).x; acc[3][1]+=(ALo).w*(W_).y;             \
    acc[3][2]+=(ALo).w*(W_).z; acc[3][3]+=(ALo).w*(W_).w;             \
    acc[4][0]+=(AHi).x*(W_).x; acc[4][1]+=(AHi).x*(W_).y;             \
    acc[4][2]+=(AHi).x*(W_).z; acc[4][3]+=(AHi).x*(W_).w;             \
    acc[5][0]+=(AHi).y*(W_).x; acc[5][1]+=(AHi).y*(W_).y;             \
    acc[5][2]+=(AHi).y*(W_).z; acc[5][3]+=(AHi).y*(W_).w;             \
    acc[6][0]+=(AHi).z*(W_).x; acc[6][1]+=(AHi).z*(W_).y;             \
    acc[6][2]+=(AHi).z*(W_).z; acc[6][3]+=(AHi).z*(W_).w;             \
    acc[7][0]+=(AHi).w*(W_).x; acc[7][1]+=(AHi).w*(W_).y;             \
    acc[7][2]+=(AHi).w*(W_).z; acc[7][3]+=(AHi).w*(W_).w;             \
}while(0)

// pair-stream residual update: px = tanh(px @ wp + b) + px  (all f32, registers)
// k-loop unroll capped at 4: limits in-flight LDS weight loads (round-8 spill fix)
__device__ __forceinline__ void pair_update(float (&px)[32], const float (*wp)[32], const float* bpb){
    float a2[32];
#pragma unroll
    for (int f=0;f<32;f++) a2[f] = bpb[f];
#pragma unroll 4
    for (int k=0;k<32;k++){
        float xk = px[k];
        const float4* wr = (const float4*)wp[k];
#pragma unroll
        for (int c=0;c<8;c++){
            float4 w = wr[c];
            a2[c*4+0] += xk*w.x; a2[c*4+1] += xk*w.y;
            a2[c*4+2] += xk*w.z; a2[c*4+3] += xk*w.w;
        }
    }
#pragma unroll
    for (int f=0;f<32;f++) px[f] = tanh_fast(a2[f]) + px[f];
}

// ---------------- prep: Wcu = Wu@Wwu, bcu = bu@Wwu+bwu; same for down spin ----
// ws layout (floats): [0,4096) Wcu  [4096,4112) bcu  [4112,8208) Wcd  [8208,8224) bcd
__global__ __launch_bounds__(512) void fermi_prep(
    const float* __restrict__ Wu, const float* __restrict__ bu,
    const float* __restrict__ Wd, const float* __restrict__ bd,
    const float* __restrict__ Wwu, const float* __restrict__ bwu,
    const float* __restrict__ Wwd, const float* __restrict__ bwd,
    float* __restrict__ ws)
{
    const int t = threadIdx.x;
    const int m = t & 255;
    const int half = t >> 8;
    const float* Wbig = half ? Wd : Wu;
    const float* Wsm  = half ? Wwd : Wwu;
    float acc[16];
#pragma unroll
    for (int k=0;k<16;k++) acc[k]=0.f;
    for (int h=0; h<128; h++){
        float wv = Wbig[m*128+h];
        const float4* wr = (const float4*)(Wsm + h*16);
        float4 a0=wr[0], a1=wr[1], a2=wr[2], a3=wr[3];
        acc[0]+=wv*a0.x; acc[1]+=wv*a0.y; acc[2]+=wv*a0.z; acc[3]+=wv*a0.w;
        acc[4]+=wv*a1.x; acc[5]+=wv*a1.y; acc[6]+=wv*a1.z; acc[7]+=wv*a1.w;
        acc[8]+=wv*a2.x; acc[9]+=wv*a2.y; acc[10]+=wv*a2.z; acc[11]+=wv*a2.w;
        acc[12]+=wv*a3.x; acc[13]+=wv*a3.y; acc[14]+=wv*a3.z; acc[15]+=wv*a3.w;
    }
    float* dst = ws + half*4112;
#pragma unroll
    for (int k=0;k<16;k++) dst[m*16+k]=acc[k];
    if (m < 16){
        const float* bbig = half ? bd : bu;
        float b2 = half ? bwd[m] : bwu[m];
        for (int h=0;h<128;h++) b2 += bbig[h]*Wsm[h*16+m];
        dst[4096+m] = b2;
    }
}

// ---------------- main: ONE walker per 256-thread block ---------------------
// LDS ~78 KB -> TWO independent blocks co-reside per CU (same 8 waves total):
// block A's barriers/GEMV overlap block B's GEMM, hiding the barrier
// serialization that pinned VALUBusy at ~39% (rounds 8-11, 1 block/CU).
// waves_per_eu(2,2) keeps the allocator at the 128-VGPR cap (round-8 fix).
__global__ __launch_bounds__(256) __attribute__((amdgpu_waves_per_eu(2,2))) void fermi_main(
    const float* __restrict__ r,   const float* __restrict__ A,
    const float* __restrict__ Ws0, const float* __restrict__ bs0,
    const float* __restrict__ Wp0, const float* __restrict__ bp0,
    const float* __restrict__ Ws1, const float* __restrict__ bs1,
    const float* __restrict__ Wp1, const float* __restrict__ bp1,
    const float* __restrict__ Ws2, const float* __restrict__ bs2,
    const float* __restrict__ Wp2, const float* __restrict__ bp2,
    const float* __restrict__ Ws3, const float* __restrict__ bs3,
    const float* __restrict__ Wc,  float* __restrict__ out)
{
    __shared__ __align__(16) float svT[256][36];      // 36.9 KB [feat][electron]
    __shared__ __align__(16) float pmuT[3][32][32];   // 12.3 KB [f][j]
    __shared__ __align__(16) float pmdT[3][32][32];   // 12.3 KB
    __shared__ __align__(16) float pool[768];         // su|sd|csh ; orb overlay in F1/F2
    __shared__ __align__(16) float wp0s[4][32];
    __shared__ __align__(16) float wp1s[32][32];
    __shared__ __align__(16) float wp2s[32][32];
    __shared__ __align__(16) float bp0s[32], bp1s[32], bp2s[32];
    __shared__ float rs[32][3];
    __shared__ __align__(16) float s0T[16][32];       // [feat][electron]
    __shared__ float ralen[32][4];
    __shared__ float envs[32];
    __shared__ __align__(16) float pu0T[4][32];
    __shared__ __align__(16) float pd0T[4][32];
    __shared__ float su0[16], sd0[16];
    __shared__ float rbar[2][3];
    __shared__ float red[2];

    const int t = threadIdx.x;
    const int b = blockIdx.x;

    const int ln  = t & 63;
    const int wv  = t >> 6;                 // wave 0..3
    const int e0  = (ln >> 4) * 8;          // electron base 0,8,16,24
    const int n0g = wv*64 + (ln & 15)*4;    // col base, covers 0..255

    float* su  = pool;          // [256]
    float* sd  = pool + 256;    // [256]
    float* csh = pool + 512;    // [256]

    // ---- A1: load r, stage ALL pair weights/biases ----
    if (t < 96) rs[t/3][t%3] = r[(size_t)b*96 + t];
    if (t < 128) (&wp0s[0][0])[t] = Wp0[t];
    {
        float* w1 = &wp1s[0][0];
        w1[t]     = Wp1[t];     w1[t+256] = Wp1[t+256];
        w1[t+512] = Wp1[t+512]; w1[t+768] = Wp1[t+768];
        float* w2 = &wp2s[0][0];
        w2[t]     = Wp2[t];     w2[t+256] = Wp2[t+256];
        w2[t+512] = Wp2[t+512]; w2[t+768] = Wp2[t+768];
    }
    if (t >= 128 && t < 160) bp0s[t-128] = bp0[t-128];
    else if (t >= 160 && t < 192) bp1s[t-160] = bp1[t-160];
    else if (t >= 192 && t < 224) bp2s[t-192] = bp2[t-192];
    __syncthreads();

    // ---- A2: electron-atom features (transposed store) ----
    if (t < 128){
        int e = t >> 2, aa = t & 3;
        float dx = rs[e][0]-A[aa*3+0];
        float dy = rs[e][1]-A[aa*3+1];
        float dz = rs[e][2]-A[aa*3+2];
        float l2 = sqrtf(dx*dx+dy*dy+dz*dz);
        s0T[aa*4+0][e]=dx; s0T[aa*4+1][e]=dy;
        s0T[aa*4+2][e]=dz; s0T[aa*4+3][e]=l2;
        ralen[e][aa]=l2;
    }
    __syncthreads();

    // ---- A3: env, su0/sd0, rbar ----
    if (t < 32){
        envs[t] = expf(-ralen[t][0])+expf(-ralen[t][1])+expf(-ralen[t][2])+expf(-ralen[t][3]);
    } else if (t < 48){
        int k = t-32; float s=0.f;
        for (int j=0;j<16;j++) s += s0T[k][j];
        su0[k] = s*(1.f/16.f);
    } else if (t < 64){
        int k = t-48; float s=0.f;
        for (int j=16;j<32;j++) s += s0T[k][j];
        sd0[k] = s*(1.f/16.f);
    } else if (t < 70){
        int q = t-64; int half=q/3, c=q%3; float s=0.f;
        for (int i=half*16;i<half*16+16;i++) s += rs[i][c];
        rbar[half][c] = s*(1.f/16.f);
    }
    __syncthreads();

    // ---- A4: pu0/pd0 (transposed) + layer-0 shared GEMV ----
    if (t < 64){
        int j = t & 31, half = t >> 5;
        float vx = rs[j][0]-rbar[half][0];
        float vy = rs[j][1]-rbar[half][1];
        float vz = rs[j][2]-rbar[half][2];
        float s=0.f; int base = half*16;
        for (int i=base;i<base+16;i++){
            if (i != j){
                float dx=rs[j][0]-rs[i][0];
                float dy=rs[j][1]-rs[i][1];
                float dz=rs[j][2]-rs[i][2];
                s += sqrtf(dx*dx+dy*dy+dz*dz);
            }
        }
        float (*dst)[32] = half ? pd0T : pu0T;
        dst[0][j]=vx; dst[1][j]=vy; dst[2][j]=vz; dst[3][j]=s*(1.f/16.f);
    }
    {
        int n = t;
        float a0 = bs0[n];
        for (int k=0;k<16;k++){
            a0 += su0[k]*Ws0[k*256+n] + sd0[k]*Ws0[(16+k)*256+n];
        }
        csh[n] = a0;
    }
    __syncthreads();

    // ================= PAIR PHASE (4 sequential px[32] passes) =================
    {
        const int i1  = t & 15;
        const int jj4 = (t >> 4) & 15;
#pragma unroll 1
        for (int pass=0; pass<4; ++pass){
            const int h   = pass >> 1;
            const int jjs = jj4 + (pass & 1)*16;
            const int ii  = i1 + h*16;
            float px[32];
            {
                float dx = rs[jjs][0]-rs[ii][0];
                float dy = rs[jjs][1]-rs[ii][1];
                float dz = rs[jjs][2]-rs[ii][2];
                float l2 = sqrtf(dx*dx+dy*dy+dz*dz);
#pragma unroll
                for (int c=0; c<8; c++){
                    float4 w0 = ((const float4*)wp0s[0])[c];
                    float4 w1 = ((const float4*)wp0s[1])[c];
                    float4 w2 = ((const float4*)wp0s[2])[c];
                    float4 w3 = ((const float4*)wp0s[3])[c];
                    float4 bb = ((const float4*)bp0s)[c];
                    px[c*4+0] = tanh_fast(bb.x + dx*w0.x + dy*w1.x + dz*w2.x + l2*w3.x);
                    px[c*4+1] = tanh_fast(bb.y + dx*w0.y + dy*w1.y + dz*w2.y + l2*w3.y);
                    px[c*4+2] = tanh_fast(bb.z + dx*w0.z + dy*w1.z + dz*w2.z + l2*w3.z);
                    px[c*4+3] = tanh_fast(bb.w + dx*w0.w + dy*w1.w + dz*w2.w + l2*w3.w);
                }
            }
            float (*pm)[32][32] = h ? pmdT : pmuT;
#pragma unroll 1
            for (int s=0; s<3; ++s){
#pragma unroll
                for (int f=0; f<32; f++){
                    float a_ = px[f];
                    a_ += __shfl_xor(a_,1); a_ += __shfl_xor(a_,2);
                    a_ += __shfl_xor(a_,4); a_ += __shfl_xor(a_,8);
                    if (i1 == 0) pm[s][f][jjs] = a_*(1.f/16.f);   // transposed [f][j]
                }
                if (s == 0)      pair_update(px, wp1s, bp1s);
                else if (s == 1) pair_update(px, wp2s, bp2s);
            }
        }
    }
    __syncthreads();

    // ================= SINGLE-STREAM PHASE =================

    // A5: layer-0 GEMM (K=24) -> svT
    {
        float acc[8][4];
#pragma unroll
        for (int e=0;e<8;e++)
#pragma unroll
            for (int n=0;n<4;n++) acc[e][n] = csh[n0g+n];
#pragma unroll
        for (int rr=0; rr<4; ++rr){
            float4 w  = *(const float4*)(Ws0 + (32+rr)*256 + n0g);
            float4 lo = *(const float4*)&pu0T[rr][e0];
            float4 hi = *(const float4*)&pu0T[rr][e0+4];
            ROWT8(lo, hi, w);
        }
#pragma unroll
        for (int rr=0; rr<4; ++rr){
            float4 w  = *(const float4*)(Ws0 + (36+rr)*256 + n0g);
            float4 lo = *(const float4*)&pd0T[rr][e0];
            float4 hi = *(const float4*)&pd0T[rr][e0+4];
            ROWT8(lo, hi, w);
        }
#pragma unroll 4
        for (int rr=0; rr<16; ++rr){
            float4 w  = *(const float4*)(Ws0 + (40+rr)*256 + n0g);
            float4 lo = *(const float4*)&s0T[rr][e0];
            float4 hi = *(const float4*)&s0T[rr][e0+4];
            ROWT8(lo, hi, w);
        }
#pragma unroll
        for (int n=0;n<4;n++){
            float4 v0 = { tanh_fast(acc[0][n]), tanh_fast(acc[1][n]),
                          tanh_fast(acc[2][n]), tanh_fast(acc[3][n]) };
            float4 v1 = { tanh_fast(acc[4][n]), tanh_fast(acc[5][n]),
                          tanh_fast(acc[6][n]), tanh_fast(acc[7][n]) };
            *(float4*)&svT[n0g+n][e0]   = v0;
            *(float4*)&svT[n0g+n][e0+4] = v1;
        }
    }
    __syncthreads();

    // S loop: layers 1..3
#pragma unroll 1
    for (int l=1; l<=3; l++){
        const float* Wl  = (l==1)?Ws1:(l==2)?Ws2:Ws3;
        const float* bl  = (l==1)?bs1:(l==2)?bs2:bs3;

        // su/sd means from transposed sv (thread t owns feature k=t)
        {
            int k = t;
            const float4* rowp = (const float4*)&svT[k][0];
            float4 a0=rowp[0], a1=rowp[1], a2=rowp[2], a3=rowp[3];
            float4 a4=rowp[4], a5=rowp[5], a6=rowp[6], a7=rowp[7];
            float s1 = (a0.x+a0.y+a0.z+a0.w)+(a1.x+a1.y+a1.z+a1.w)
                     + (a2.x+a2.y+a2.z+a2.w)+(a3.x+a3.y+a3.z+a3.w);
            float s2 = (a4.x+a4.y+a4.z+a4.w)+(a5.x+a5.y+a5.z+a5.w)
                     + (a6.x+a6.y+a6.z+a6.w)+(a7.x+a7.y+a7.z+a7.w);
            su[k] = s1*(1.f/16.f);
            sd[k] = s2*(1.f/16.f);
        }
        __syncthreads();

        // shared-part GEMV (both halves per thread; no partial-sum barrier)
        {
            int n = t;
            float a0 = bl[n];
#pragma unroll 4
            for (int k=0;k<256;k++) a0 += su[k]*Wl[k*256+n];
#pragma unroll 4
            for (int k=0;k<256;k++) a0 += sd[k]*Wl[(256+k)*256+n];
            csh[n] = a0;
        }
        __syncthreads();

        // per-electron GEMM: K = 32(pu)+32(pd)+256(sv)
        float acc[8][4];
#pragma unroll
        for (int e=0;e<8;e++)
#pragma unroll
            for (int n=0;n<4;n++) acc[e][n] = csh[n0g+n];
        {
            const float (*puA)[32] = pmuT[l-1];
            const float (*pdA)[32] = pmdT[l-1];
#pragma unroll 4
            for (int R=0; R<32; ++R){
                float4 w  = *(const float4*)(Wl + (512+R)*256 + n0g);
                float4 lo = *(const float4*)&puA[R][e0];
                float4 hi = *(const float4*)&puA[R][e0+4];
                ROWT8(lo, hi, w);
            }
#pragma unroll 4
            for (int R=0; R<32; ++R){
                float4 w  = *(const float4*)(Wl + (544+R)*256 + n0g);
                float4 lo = *(const float4*)&pdA[R][e0];
                float4 hi = *(const float4*)&pdA[R][e0+4];
                ROWT8(lo, hi, w);
            }
        }
#pragma unroll 4
        for (int R=0; R<256; ++R){
            float4 w  = *(const float4*)(Wl + (576+R)*256 + n0g);
            float4 lo = *(const float4*)&svT[R][e0];
            float4 hi = *(const float4*)&svT[R][e0+4];
            ROWT8(lo, hi, w);
        }
        __syncthreads();

        // residual write of svT
#pragma unroll
        for (int n=0;n<4;n++){
            float4 o0 = *(const float4*)&svT[n0g+n][e0];
            float4 o1 = *(const float4*)&svT[n0g+n][e0+4];
            float4 v0 = { tanh_fast(acc[0][n])+o0.x, tanh_fast(acc[1][n])+o0.y,
                          tanh_fast(acc[2][n])+o0.z, tanh_fast(acc[3][n])+o0.w };
            float4 v1 = { tanh_fast(acc[4][n])+o1.x, tanh_fast(acc[5][n])+o1.y,
                          tanh_fast(acc[6][n])+o1.z, tanh_fast(acc[7][n])+o1.w };
            *(float4*)&svT[n0g+n][e0]   = v0;
            *(float4*)&svT[n0g+n][e0+4] = v1;
        }
        __syncthreads();
    }

    // F1: orbitals via folded weights (2 halves x 16x16), orb overlays pool
#pragma unroll 1
    for (int rep=0; rep<2; ++rep){
        int idx = t + rep*256;
        int half = idx >> 8, il = (idx >> 4) & 15, k16 = idx & 15;
        int row = half*16 + il;
        const float* WcT = Wc + half*4112;
        float a0 = WcT[4096 + k16];
#pragma unroll 8
        for (int m=0;m<256;m++) a0 += svT[m][row]*WcT[m*16+k16];
        // defer store: csh region still live for rep? csh dead after layer 3.
        pool[half*272 + il*17 + k16] = a0 * envs[row];
    }
    __syncthreads();

    // F2: 16x16 LU with partial pivoting, one wave per matrix (2 matrices)
    {
        int w = t >> 6;
        if (w < 2){
            int lane = t & 63;
            float* M = pool + w*272;   // row stride 17
            float ld_ = 0.f;
            for (int k=0;k<16;k++){
                float v = (lane>=k && lane<16) ? fabsf(M[lane*17+k]) : -1.f;
                int idx = lane;
                for (int off=32; off; off>>=1){
                    float ov = __shfl_xor(v, off);
                    int   oi = __shfl_xor(idx, off);
                    if (ov > v || (ov == v && oi < idx)){ v=ov; idx=oi; }
                }
                int p = idx;
                if (p != k && lane >= k && lane < 16){
                    float t1 = M[k*17+lane], t2 = M[p*17+lane];
                    M[k*17+lane] = t2; M[p*17+lane] = t1;
                }
                float piv = M[k*17+k];
                ld_ += logf(fabsf(piv));
                float inv = 1.f/piv;
                float rowkj = (lane<16) ? M[k*17+lane] : 0.f;
                if (lane > k && lane < 16){
                    for (int i=k+1;i<16;i++){
                        float mik = M[i*17+k]*inv;
                        M[i*17+lane] -= mik*rowkj;
                    }
                }
            }
            if (lane == 0) red[w] = ld_;
        }
    }
    __syncthreads();
    if (t == 0) out[b] = red[0] + red[1];
}

extern "C" void kernel_launch(void* const* d_in, const int* in_sizes, int n_in,
                              void* d_out, int out_size, void* d_ws, size_t ws_size,
                              hipStream_t stream) {
    const float* r   = (const float*)d_in[0];
    const float* a   = (const float*)d_in[1];
    const float* Ws0 = (const float*)d_in[2];  const float* bs0 = (const float*)d_in[3];
    const float* Wp0 = (const float*)d_in[4];  const float* bp0 = (const float*)d_in[5];
    const float* Ws1 = (const float*)d_in[6];  const float* bs1 = (const float*)d_in[7];
    const float* Wp1 = (const float*)d_in[8];  const float* bp1 = (const float*)d_in[9];
    const float* Ws2 = (const float*)d_in[10]; const float* bs2 = (const float*)d_in[11];
    const float* Wp2 = (const float*)d_in[12]; const float* bp2 = (const float*)d_in[13];
    const float* Ws3 = (const float*)d_in[14]; const float* bs3 = (const float*)d_in[15];
    const float* Wu  = (const float*)d_in[16]; const float* bu  = (const float*)d_in[17];
    const float* Wd  = (const float*)d_in[18]; const float* bd  = (const float*)d_in[19];
    const float* Wwu = (const float*)d_in[20]; const float* bwu = (const float*)d_in[21];
    const float* Wwd = (const float*)d_in[22]; const float* bwd = (const float*)d_in[23];
    float* ws = (float*)d_ws;
    float* out = (float*)d_out;

    fermi_prep<<<1, 512, 0, stream>>>(Wu, bu, Wd, bd, Wwu, bwu, Wwd, bwd, ws);
    fermi_main<<<out_size, 256, 0, stream>>>(r, a, Ws0, bs0, Wp0, bp0,
                                             Ws1, bs1, Wp1, bp1,
                                             Ws2, bs2, Wp2, bp2,
                                             Ws3, bs3, ws, out);
}

// Round 13
// 1443.461 us; speedup vs baseline: 1.1582x; 1.1582x over previous
//
#include <hip/hip_runtime.h>
#include <hip/hip_bf16.h>

__device__ __forceinline__ float tanh_fast(float x){
    float e = __expf(2.0f*x);
    return 1.0f - 2.0f/(e + 1.0f);
}

#define FMA16A(ACC, W_, A_, B_, C_, D_) do{                      \
    ACC[0][0] += (A_)*(W_).x; ACC[0][1] += (A_)*(W_).y;          \
    ACC[0][2] += (A_)*(W_).z; ACC[0][3] += (A_)*(W_).w;          \
    ACC[1][0] += (B_)*(W_).x; ACC[1][1] += (B_)*(W_).y;          \
    ACC[1][2] += (B_)*(W_).z; ACC[1][3] += (B_)*(W_).w;          \
    ACC[2][0] += (C_)*(W_).x; ACC[2][1] += (C_)*(W_).y;          \
    ACC[2][2] += (C_)*(W_).z; ACC[2][3] += (C_)*(W_).w;          \
    ACC[3][0] += (D_)*(W_).x; ACC[3][1] += (D_)*(W_).y;          \
    ACC[3][2] += (D_)*(W_).z; ACC[3][3] += (D_)*(W_).w;          \
}while(0)

// one weight row (float4 at col n0) shared by BOTH walkers' 4x4 accumulators
#define ROW2(Wb, R_, c_, A0,A1,A2,A3, B0,B1,B2,B3) do{                        \
    float4 w_ = *(const float4*)((Wb) + (R_)*256 + n0);                       \
    FMA16A(acc0, w_, (A0).c_,(A1).c_,(A2).c_,(A3).c_);                        \
    FMA16A(acc1, w_, (B0).c_,(B1).c_,(B2).c_,(B3).c_);                        \
}while(0)

#define G4D(Wb, R0, A0,A1,A2,A3, B0,B1,B2,B3) do{                \
    ROW2(Wb, (R0)+0, x, A0,A1,A2,A3, B0,B1,B2,B3);               \
    ROW2(Wb, (R0)+1, y, A0,A1,A2,A3, B0,B1,B2,B3);               \
    ROW2(Wb, (R0)+2, z, A0,A1,A2,A3, B0,B1,B2,B3);               \
    ROW2(Wb, (R0)+3, w, A0,A1,A2,A3, B0,B1,B2,B3);               \
}while(0)

// 4 preloaded weight rows (w0..w3) against 8 activation float4s (2 walkers)
#define G4P(w0,w1,w2,w3, A0,A1,A2,A3, B0,B1,B2,B3) do{                                   \
    FMA16A(acc0, w0, (A0).x,(A1).x,(A2).x,(A3).x);                                       \
    FMA16A(acc1, w0, (B0).x,(B1).x,(B2).x,(B3).x);                                       \
    FMA16A(acc0, w1, (A0).y,(A1).y,(A2).y,(A3).y);                                       \
    FMA16A(acc1, w1, (B0).y,(B1).y,(B2).y,(B3).y);                                       \
    FMA16A(acc0, w2, (A0).z,(A1).z,(A2).z,(A3).z);                                       \
    FMA16A(acc1, w2, (B0).z,(B1).z,(B2).z,(B3).z);                                       \
    FMA16A(acc0, w3, (A0).w,(A1).w,(A2).w,(A3).w);                                       \
    FMA16A(acc1, w3, (B0).w,(B1).w,(B2).w,(B3).w);                                       \
}while(0)

// pair-stream residual update: px = tanh(px @ wp + b) + px   (all f32, registers)
// k-loop unroll capped at 4: limits in-flight LDS weight loads (round-8 spill fix)
__device__ __forceinline__ void pair_update(float (&px)[32], const float (*wp)[32], const float* bpb){
    float a2[32];
#pragma unroll
    for (int f=0;f<32;f++) a2[f] = bpb[f];
#pragma unroll 4
    for (int k=0;k<32;k++){
        float xk = px[k];
        const float4* wr = (const float4*)wp[k];
#pragma unroll
        for (int c=0;c<8;c++){
            float4 w = wr[c];
            a2[c*4+0] += xk*w.x; a2[c*4+1] += xk*w.y;
            a2[c*4+2] += xk*w.z; a2[c*4+3] += xk*w.w;
        }
    }
#pragma unroll
    for (int f=0;f<32;f++) px[f] = tanh_fast(a2[f]) + px[f];
}

// ---------------- prep: Wcu = Wu@Wwu, bcu = bu@Wwu+bwu; same for down spin ----
// ws layout (floats): [0,4096) Wcu  [4096,4112) bcu  [4112,8208) Wcd  [8208,8224) bcd
__global__ __launch_bounds__(512) void fermi_prep(
    const float* __restrict__ Wu, const float* __restrict__ bu,
    const float* __restrict__ Wd, const float* __restrict__ bd,
    const float* __restrict__ Wwu, const float* __restrict__ bwu,
    const float* __restrict__ Wwd, const float* __restrict__ bwd,
    float* __restrict__ ws)
{
    const int t = threadIdx.x;
    const int m = t & 255;
    const int half = t >> 8;
    const float* Wbig = half ? Wd : Wu;
    const float* Wsm  = half ? Wwd : Wwu;
    float acc[16];
#pragma unroll
    for (int k=0;k<16;k++) acc[k]=0.f;
    for (int h=0; h<128; h++){
        float wv = Wbig[m*128+h];
        const float4* wr = (const float4*)(Wsm + h*16);
        float4 a0=wr[0], a1=wr[1], a2=wr[2], a3=wr[3];
        acc[0]+=wv*a0.x; acc[1]+=wv*a0.y; acc[2]+=wv*a0.z; acc[3]+=wv*a0.w;
        acc[4]+=wv*a1.x; acc[5]+=wv*a1.y; acc[6]+=wv*a1.z; acc[7]+=wv*a1.w;
        acc[8]+=wv*a2.x; acc[9]+=wv*a2.y; acc[10]+=wv*a2.z; acc[11]+=wv*a2.w;
        acc[12]+=wv*a3.x; acc[13]+=wv*a3.y; acc[14]+=wv*a3.z; acc[15]+=wv*a3.w;
    }
    float* dst = ws + half*4112;
#pragma unroll
    for (int k=0;k<16;k++) dst[m*16+k]=acc[k];
    if (m < 16){
        const float* bbig = half ? bd : bu;
        float b2 = half ? bwd[m] : bwu[m];
        for (int h=0;h<128;h++) b2 += bbig[h]*Wsm[h*16+m];
        dst[4096+m] = b2;
    }
}

// ---------------- main: TWO walkers per block (round-10 base) ---------------
// NEW (round 13): software-pipelined weight prefetch in the sv-GEMM (hold next
// 4-row group's float4s in regs; FMA on previous copies) + unroll-8 GEMV.
// Rationale: unroll-1 loop exposed full L2 latency per iteration (no modulo
// scheduling in the backend); VALUBusy was pinned ~40% across rounds 8-12.
__global__ __launch_bounds__(512) __attribute__((amdgpu_waves_per_eu(2,2))) void fermi_main(
    const float* __restrict__ r,   const float* __restrict__ A,
    const float* __restrict__ Ws0, const float* __restrict__ bs0,
    const float* __restrict__ Wp0, const float* __restrict__ bp0,
    const float* __restrict__ Ws1, const float* __restrict__ bs1,
    const float* __restrict__ Wp1, const float* __restrict__ bp1,
    const float* __restrict__ Ws2, const float* __restrict__ bs2,
    const float* __restrict__ Wp2, const float* __restrict__ bp2,
    const float* __restrict__ Ws3, const float* __restrict__ bs3,
    const float* __restrict__ Wc,  float* __restrict__ out)
{
    __shared__ __align__(16) float sv2[2][32][256];     // 64 KB
    __shared__ __align__(16) float pmu2[2][3][32][32];  // 24 KB
    __shared__ __align__(16) float pmd2[2][3][32][32];  // 24 KB
    __shared__ __align__(16) float su2[2][256];
    __shared__ __align__(16) float sd2[2][256];
    __shared__ __align__(16) float pool[1536];          // cpart[2][2][256]|csh@1024 ; orb overlay
    __shared__ __align__(16) float wp0s[4][32];
    __shared__ __align__(16) float wp1s[32][32];
    __shared__ __align__(16) float wp2s[32][32];
    __shared__ __align__(16) float bp0s[32], bp1s[32], bp2s[32];
    __shared__ float rs2[2][32][3];
    __shared__ __align__(16) float s02[2][32][16];
    __shared__ float ralen2[2][32][4];
    __shared__ float envs2[2][32];
    __shared__ __align__(16) float pu02[2][32][4];
    __shared__ __align__(16) float pd02[2][32][4];
    __shared__ float su02[2][16], sd02[2][16];
    __shared__ float rbar2[2][2][3];
    __shared__ float red2[2][2];

    const int t = threadIdx.x;
    const int b = blockIdx.x;

    const int n0 = (t & 63) * 4;        // GEMM cols n0..n0+3
    const int j0 = (t >> 6) * 4;        // electron group (same for both walkers)

    float* cpart = pool;                // [2][2][256]
    float* cshf  = pool + 1024;         // [2][256]

    // ---- A1: load r (2 walkers), stage ALL pair weights/biases ----
    if (t < 192) (&rs2[0][0][0])[t] = r[(size_t)b*192 + t];
    if (t < 128) (&wp0s[0][0])[t] = Wp0[t];
    {
        float* w1 = &wp1s[0][0];
        w1[t]     = Wp1[t];
        w1[t+512] = Wp1[t+512];
        float* w2 = &wp2s[0][0];
        w2[t]     = Wp2[t];
        w2[t+512] = Wp2[t+512];
    }
    if (t >= 192 && t < 224) bp0s[t-192] = bp0[t-192];
    else if (t >= 224 && t < 256) bp1s[t-224] = bp1[t-224];
    else if (t >= 256 && t < 288) bp2s[t-256] = bp2[t-256];
    __syncthreads();

    // ---- A2: electron-atom features (2 walkers x 32e x 4a) ----
    if (t < 256){
        int wk = t >> 7, q = t & 127;
        int e = q >> 2, aa = q & 3;
        float dx = rs2[wk][e][0]-A[aa*3+0];
        float dy = rs2[wk][e][1]-A[aa*3+1];
        float dz = rs2[wk][e][2]-A[aa*3+2];
        float ln = sqrtf(dx*dx+dy*dy+dz*dz);
        s02[wk][e][aa*4+0]=dx; s02[wk][e][aa*4+1]=dy;
        s02[wk][e][aa*4+2]=dz; s02[wk][e][aa*4+3]=ln;
        ralen2[wk][e][aa]=ln;
    }
    __syncthreads();

    // ---- A3: env, su0/sd0, rbar ----
    if (t < 64){
        int wk = t >> 5, e = t & 31;
        envs2[wk][e] = expf(-ralen2[wk][e][0])+expf(-ralen2[wk][e][1])
                     + expf(-ralen2[wk][e][2])+expf(-ralen2[wk][e][3]);
    } else if (t < 128){
        int q = t-64; int wk = q >> 5, half = (q >> 4) & 1, k = q & 15;
        float s = 0.f; int jb = half*16;
        for (int j=jb; j<jb+16; j++) s += s02[wk][j][k];
        (half ? sd02 : su02)[wk][k] = s*(1.f/16.f);
    } else if (t < 140){
        int q = t-128; int wk = q/6, rr_ = q%6, half = rr_/3, c = rr_%3;
        float s=0.f;
        for (int i=half*16;i<half*16+16;i++) s += rs2[wk][i][c];
        rbar2[wk][half][c] = s*(1.f/16.f);
    }
    __syncthreads();

    // ---- A4: pu0/pd0 (t<128) + layer-0 shared GEMV (all threads) ----
    if (t < 128){
        int wk = t >> 6, q = t & 63;
        int j = q & 31, half = q >> 5;
        float* dst = (half ? pd02 : pu02)[wk][j];
        dst[0] = rs2[wk][j][0]-rbar2[wk][half][0];
        dst[1] = rs2[wk][j][1]-rbar2[wk][half][1];
        dst[2] = rs2[wk][j][2]-rbar2[wk][half][2];
        float s=0.f; int base = half*16;
        for (int i=base;i<base+16;i++){
            if (i != j){
                float dx=rs2[wk][j][0]-rs2[wk][i][0];
                float dy=rs2[wk][j][1]-rs2[wk][i][1];
                float dz=rs2[wk][j][2]-rs2[wk][i][2];
                s += sqrtf(dx*dx+dy*dy+dz*dz);
            }
        }
        dst[3] = s*(1.f/16.f);
    }
    {
        int wk = t >> 8, n = t & 255;
        float a0 = bs0[n];
        for (int k=0;k<16;k++){
            a0 += su02[wk][k]*Ws0[k*256+n] + sd02[wk][k]*Ws0[(16+k)*256+n];
        }
        cshf[wk*256+n] = a0;
    }
    __syncthreads();

    // ================= PAIR PHASE (4 sequential px[32] passes) =================
    {
        const int i1  = t & 15;
        const int jj4 = (t >> 4) & 15;
        const int wkp = t >> 8;
#pragma unroll 1
        for (int pass=0; pass<4; ++pass){
            const int h   = pass >> 1;
            const int jjs = jj4 + (pass & 1)*16;
            const int ii  = i1 + h*16;
            float px[32];
            {
                float dx = rs2[wkp][jjs][0]-rs2[wkp][ii][0];
                float dy = rs2[wkp][jjs][1]-rs2[wkp][ii][1];
                float dz = rs2[wkp][jjs][2]-rs2[wkp][ii][2];
                float ln = sqrtf(dx*dx+dy*dy+dz*dz);
#pragma unroll
                for (int c=0; c<8; c++){
                    float4 w0 = ((const float4*)wp0s[0])[c];
                    float4 w1 = ((const float4*)wp0s[1])[c];
                    float4 w2 = ((const float4*)wp0s[2])[c];
                    float4 w3 = ((const float4*)wp0s[3])[c];
                    float4 bb = ((const float4*)bp0s)[c];
                    px[c*4+0] = tanh_fast(bb.x + dx*w0.x + dy*w1.x + dz*w2.x + ln*w3.x);
                    px[c*4+1] = tanh_fast(bb.y + dx*w0.y + dy*w1.y + dz*w2.y + ln*w3.y);
                    px[c*4+2] = tanh_fast(bb.z + dx*w0.z + dy*w1.z + dz*w2.z + ln*w3.z);
                    px[c*4+3] = tanh_fast(bb.w + dx*w0.w + dy*w1.w + dz*w2.w + ln*w3.w);
                }
            }
            float (*pm)[32][32] = h ? pmd2[wkp] : pmu2[wkp];
#pragma unroll 1
            for (int s=0; s<3; ++s){
#pragma unroll
                for (int f=0; f<32; f++){
                    float a_ = px[f];
                    a_ += __shfl_xor(a_,1); a_ += __shfl_xor(a_,2);
                    a_ += __shfl_xor(a_,4); a_ += __shfl_xor(a_,8);
                    if (i1 == 0) pm[s][jjs][f] = a_*(1.f/16.f);
                }
                if (s == 0)      pair_update(px, wp1s, bp1s);
                else if (s == 1) pair_update(px, wp2s, bp2s);
            }
        }
    }
    __syncthreads();

    // ================= SINGLE-STREAM PHASE =================

    // A5: layer-0 GEMM (K=24) -> sv, both walkers share weight rows
    {
        float acc0[4][4], acc1[4][4];
#pragma unroll
        for (int e=0;e<4;e++)
#pragma unroll
            for (int n=0;n<4;n++){ acc0[e][n] = cshf[n0+n]; acc1[e][n] = cshf[256+n0+n]; }
        {
            float4 A0 = *(const float4*)pu02[0][j0+0];
            float4 A1 = *(const float4*)pu02[0][j0+1];
            float4 A2 = *(const float4*)pu02[0][j0+2];
            float4 A3 = *(const float4*)pu02[0][j0+3];
            float4 B0 = *(const float4*)pu02[1][j0+0];
            float4 B1 = *(const float4*)pu02[1][j0+1];
            float4 B2 = *(const float4*)pu02[1][j0+2];
            float4 B3 = *(const float4*)pu02[1][j0+3];
            G4D(Ws0, 32, A0,A1,A2,A3, B0,B1,B2,B3);
            A0 = *(const float4*)pd02[0][j0+0];
            A1 = *(const float4*)pd02[0][j0+1];
            A2 = *(const float4*)pd02[0][j0+2];
            A3 = *(const float4*)pd02[0][j0+3];
            B0 = *(const float4*)pd02[1][j0+0];
            B1 = *(const float4*)pd02[1][j0+1];
            B2 = *(const float4*)pd02[1][j0+2];
            B3 = *(const float4*)pd02[1][j0+3];
            G4D(Ws0, 36, A0,A1,A2,A3, B0,B1,B2,B3);
        }
#pragma unroll
        for (int k4=0;k4<4;k4++){
            float4 A0 = ((const float4*)s02[0][j0+0])[k4];
            float4 A1 = ((const float4*)s02[0][j0+1])[k4];
            float4 A2 = ((const float4*)s02[0][j0+2])[k4];
            float4 A3 = ((const float4*)s02[0][j0+3])[k4];
            float4 B0 = ((const float4*)s02[1][j0+0])[k4];
            float4 B1 = ((const float4*)s02[1][j0+1])[k4];
            float4 B2 = ((const float4*)s02[1][j0+2])[k4];
            float4 B3 = ((const float4*)s02[1][j0+3])[k4];
            G4D(Ws0, 40+k4*4, A0,A1,A2,A3, B0,B1,B2,B3);
        }
#pragma unroll
        for (int e=0;e<4;e++)
#pragma unroll
            for (int n=0;n<4;n++){
                sv2[0][j0+e][n0+n] = tanh_fast(acc0[e][n]);
                sv2[1][j0+e][n0+n] = tanh_fast(acc1[e][n]);
            }
    }
    __syncthreads();

    // S loop: layers 1..3
#pragma unroll 1
    for (int l=1; l<=3; l++){
        const float* Wl  = (l==1)?Ws1:(l==2)?Ws2:Ws3;
        const float* bl  = (l==1)?bs1:(l==2)?bs2:bs3;

        // su/sd means (both halves, per walker)
        {
            int wk = t >> 8, k = t & 255;
            float s1=0.f, s2=0.f;
            for (int j=0;j<16;j++)  s1 += sv2[wk][j][k];
            for (int j=16;j<32;j++) s2 += sv2[wk][j][k];
            su2[wk][k] = s1*(1.f/16.f);
            sd2[wk][k] = s2*(1.f/16.f);
        }
        __syncthreads();

        // shared-part GEMV: weight element loaded ONCE for both walkers;
        // unroll 8 -> 8 outstanding L2 loads to hide latency
        {
            int h = t >> 8, n = t & 255;
            const float* Wb = Wl + h*65536;
            const float* sA = h ? sd2[0] : su2[0];
            const float* sB = h ? sd2[1] : su2[1];
            float a0 = h ? 0.f : bl[n];
            float a1 = a0;
#pragma unroll 8
            for (int k=0;k<256;k++){
                float wv = Wb[k*256+n];
                a0 += sA[k]*wv; a1 += sB[k]*wv;
            }
            cpart[(0*2+h)*256+n] = a0;
            cpart[(1*2+h)*256+n] = a1;
        }
        __syncthreads();
        {
            int wk = t >> 8, n = t & 255;
            cshf[wk*256+n] = cpart[(wk*2+0)*256+n] + cpart[(wk*2+1)*256+n];
        }
        __syncthreads();

        // per-electron GEMM, K = 32(pu)+32(pd)+256(sv), weights shared by walkers
        float acc0[4][4], acc1[4][4];
#pragma unroll
        for (int e=0;e<4;e++)
#pragma unroll
            for (int n=0;n<4;n++){ acc0[e][n] = cshf[n0+n]; acc1[e][n] = cshf[256+n0+n]; }
        const float* puA = &pmu2[0][l-1][0][0];
        const float* puB = &pmu2[1][l-1][0][0];
        const float* pdA = &pmd2[0][l-1][0][0];
        const float* pdB = &pmd2[1][l-1][0][0];
#pragma unroll
        for (int k4=0;k4<8;k4++){
            float4 A0 = ((const float4*)(puA + (j0+0)*32))[k4];
            float4 A1 = ((const float4*)(puA + (j0+1)*32))[k4];
            float4 A2 = ((const float4*)(puA + (j0+2)*32))[k4];
            float4 A3 = ((const float4*)(puA + (j0+3)*32))[k4];
            float4 B0 = ((const float4*)(puB + (j0+0)*32))[k4];
            float4 B1 = ((const float4*)(puB + (j0+1)*32))[k4];
            float4 B2 = ((const float4*)(puB + (j0+2)*32))[k4];
            float4 B3 = ((const float4*)(puB + (j0+3)*32))[k4];
            G4D(Wl, 512+k4*4, A0,A1,A2,A3, B0,B1,B2,B3);
        }
#pragma unroll
        for (int k4=0;k4<8;k4++){
            float4 A0 = ((const float4*)(pdA + (j0+0)*32))[k4];
            float4 A1 = ((const float4*)(pdA + (j0+1)*32))[k4];
            float4 A2 = ((const float4*)(pdA + (j0+2)*32))[k4];
            float4 A3 = ((const float4*)(pdA + (j0+3)*32))[k4];
            float4 B0 = ((const float4*)(pdB + (j0+0)*32))[k4];
            float4 B1 = ((const float4*)(pdB + (j0+1)*32))[k4];
            float4 B2 = ((const float4*)(pdB + (j0+2)*32))[k4];
            float4 B3 = ((const float4*)(pdB + (j0+3)*32))[k4];
            G4D(Wl, 544+k4*4, A0,A1,A2,A3, B0,B1,B2,B3);
        }
        // sv-part: software-pipelined weight prefetch (next 4-row group in regs)
        {
            const float* WbP = Wl + 576*256 + n0;
            float4 wn0 = *(const float4*)(WbP);
            float4 wn1 = *(const float4*)(WbP + 256);
            float4 wn2 = *(const float4*)(WbP + 512);
            float4 wn3 = *(const float4*)(WbP + 768);
#pragma unroll 1
            for (int k4=0;k4<64;k4++){
                float4 w0=wn0, w1=wn1, w2=wn2, w3=wn3;
                {
                    int kn = (k4 < 63) ? (k4+1) : 63;
                    const float* Wn = WbP + kn*1024;
                    wn0 = *(const float4*)(Wn);
                    wn1 = *(const float4*)(Wn + 256);
                    wn2 = *(const float4*)(Wn + 512);
                    wn3 = *(const float4*)(Wn + 768);
                }
                float4 A0 = ((const float4*)sv2[0][j0+0])[k4];
                float4 A1 = ((const float4*)sv2[0][j0+1])[k4];
                float4 A2 = ((const float4*)sv2[0][j0+2])[k4];
                float4 A3 = ((const float4*)sv2[0][j0+3])[k4];
                float4 B0 = ((const float4*)sv2[1][j0+0])[k4];
                float4 B1 = ((const float4*)sv2[1][j0+1])[k4];
                float4 B2 = ((const float4*)sv2[1][j0+2])[k4];
                float4 B3 = ((const float4*)sv2[1][j0+3])[k4];
                G4P(w0,w1,w2,w3, A0,A1,A2,A3, B0,B1,B2,B3);
            }
        }
        __syncthreads();

        // residual write of sv (both walkers)
#pragma unroll
        for (int e=0;e<4;e++)
#pragma unroll
            for (int n=0;n<4;n++){
                float o0 = sv2[0][j0+e][n0+n];
                float o1 = sv2[1][j0+e][n0+n];
                sv2[0][j0+e][n0+n] = tanh_fast(acc0[e][n]) + o0;
                sv2[1][j0+e][n0+n] = tanh_fast(acc1[e][n]) + o1;
            }
        __syncthreads();
    }

    // F1: orbitals via folded weights (2 walkers x 2 halves x 16x16)
#pragma unroll 1
    for (int rep=0; rep<2; ++rep){
        int idx = t + rep*512;
        int wk = idx >> 9, rem = idx & 511;
        int half = rem >> 8, il = (rem >> 4) & 15, k16 = rem & 15;
        int row = half*16 + il;
        const float* WcT = Wc + half*4112;
        float a0 = WcT[4096 + k16];
#pragma unroll 8
        for (int m=0;m<256;m++) a0 += sv2[wk][row][m]*WcT[m*16+k16];
        pool[(wk*2+half)*272 + il*17 + k16] = a0 * envs2[wk][row];
    }
    __syncthreads();

    // F2: 16x16 LU with partial pivoting, one wave per matrix (4 matrices)
    {
        int w = t >> 6;
        if (w < 4){
            int lane = t & 63;
            float* M = pool + w*272;   // row stride 17; w = wk*2+half
            float ld_ = 0.f;
            for (int k=0;k<16;k++){
                float v = (lane>=k && lane<16) ? fabsf(M[lane*17+k]) : -1.f;
                int idx = lane;
                for (int off=32; off; off>>=1){
                    float ov = __shfl_xor(v, off);
                    int   oi = __shfl_xor(idx, off);
                    if (ov > v || (ov == v && oi < idx)){ v=ov; idx=oi; }
                }
                int p = idx;
                if (p != k && lane >= k && lane < 16){
                    float t1 = M[k*17+lane], t2 = M[p*17+lane];
                    M[k*17+lane] = t2; M[p*17+lane] = t1;
                }
                float piv = M[k*17+k];
                ld_ += logf(fabsf(piv));
                float inv = 1.f/piv;
                float rowkj = (lane<16) ? M[k*17+lane] : 0.f;
                if (lane > k && lane < 16){
                    for (int i=k+1;i<16;i++){
                        float mik = M[i*17+k]*inv;
                        M[i*17+lane] -= mik*rowkj;
                    }
                }
            }
            if (lane == 0) red2[w>>1][w&1] = ld_;
        }
    }
    __syncthreads();
    if (t < 2) out[2*b + t] = red2[t][0] + red2[t][1];
}

extern "C" void kernel_launch(void* const* d_in, const int* in_sizes, int n_in,
                              void* d_out, int out_size, void* d_ws, size_t ws_size,
                              hipStream_t stream) {
    const float* r   = (const float*)d_in[0];
    const float* a   = (const float*)d_in[1];
    const float* Ws0 = (const float*)d_in[2];  const float* bs0 = (const float*)d_in[3];
    const float* Wp0 = (const float*)d_in[4];  const float* bp0 = (const float*)d_in[5];
    const float* Ws1 = (const float*)d_in[6];  const float* bs1 = (const float*)d_in[7];
    const float* Wp1 = (const float*)d_in[8];  const float* bp1 = (const float*)d_in[9];
    const float* Ws2 = (const float*)d_in[10]; const float* bs2 = (const float*)d_in[11];
    const float* Wp2 = (const float*)d_in[12]; const float* bp2 = (const float*)d_in[13];
    const float* Ws3 = (const float*)d_in[14]; const float* bs3 = (const float*)d_in[15];
    const float* Wu  = (const float*)d_in[16]; const float* bu  = (const float*)d_in[17];
    const float* Wd  = (const float*)d_in[18]; const float* bd  = (const float*)d_in[19];
    const float* Wwu = (const float*)d_in[20]; const float* bwu = (const float*)d_in[21];
    const float* Wwd = (const float*)d_in[22]; const float* bwd = (const float*)d_in[23];
    float* ws = (float*)d_ws;
    float* out = (float*)d_out;

    fermi_prep<<<1, 512, 0, stream>>>(Wu, bu, Wd, bd, Wwu, bwu, Wwd, bwd, ws);
    fermi_main<<<out_size/2, 512, 0, stream>>>(r, a, Ws0, bs0, Wp0, bp0,
                                               Ws1, bs1, Wp1, bp1,
                                               Ws2, bs2, Wp2, bp2,
                                               Ws3, bs3, ws, out);
}